// Round 18
// baseline (73.744 us; speedup 1.0000x reference)
//
#include <hip/hip_runtime.h>
#include <hip/hip_bf16.h>
#include <math.h>

#define VOCAB 2048
#define EMB 256
#define MAXLEN 8
#define NBATCH 16
#define LAT 16

typedef unsigned short u16;
typedef unsigned int u32;
using bf16x8 = __attribute__((ext_vector_type(8))) short;
using f32x4  = __attribute__((ext_vector_type(4))) float;

// token = argmax_j ( j/2048 <= v && v <= (j+1)/2048 ), 0 if none.
// cumsum of uniform softmax is exactly k/2048 in fp32; v*2048 is exact.
__device__ __forceinline__ int token_of(float v) {
    float u = v * 2048.0f;
    if (!(u >= 0.0f) || u > 2048.0f) return 0;   // v<0, v>1, or NaN
    int k = (int)ceilf(u) - 1;
    return k < 0 ? 0 : k;
}

__device__ __forceinline__ float sigmoidf_(float x) { return 1.0f / (1.0f + expf(-x)); }

__device__ __forceinline__ u16 to_bf16(float x) {
    __hip_bfloat16 hb = __float2bfloat16(x);   // RTNE
    return *reinterpret_cast<u16*>(&hb);
}

// ---------------------------------------------------------------------------
// GATE-INTERLEAVED column packing: packed col c = u*4 + g  (u=c>>2, g=c&3).
// One 16-col MFMA ntile = 4 u's x 4 gates -> LSTM update is block-local,
// enabling 512 independent blocks (full chip) in the recurrent step.
// Fragment (l,i) of (nt,k0): bf16( W[(k0*32 + 8*(l>>4) + i)*8192 + gcol ] ),
// gcol = ((l&15)&3)*2048 + nt*4 + ((l&15)>>2). A-frags use the same k-map,
// so any in-fragment k-permutation cancels.
// PACK retiled for DRAM locality (round-17 lesson: 128B-granular reads at
// 32KB stride ran at ~2 TB/s): block = 8 rows x 512 u x 4 gates -> reads are
// 2KB-contiguous per (row,gate); a block's rows fall in ONE 16-lane band
// (band = kc&3) of each fragment, so it writes 256B-contiguous band slices
// for its 128 nt's. LDS [8][2048] u16: fill b128 covers all 32 banks (ideal
// 8 accesses/bank); assemble reads are 2-way (free).
// ---------------------------------------------------------------------------

// ---- K1: one-launch pack. [0,1024): Wr->BW; [1024,1152): Wk->BWk;
// [1152,1168): XA = E[token] A-fragments.
__global__ __launch_bounds__(256) void k_pack(
        const float* __restrict__ Wr, const float* __restrict__ Wk,
        const float* __restrict__ ip, const float* __restrict__ E,
        u16* __restrict__ BW, u16* __restrict__ BWk, u16* __restrict__ XA) {
    __shared__ __align__(16) u16 lds[8][2048];   // 32 KB [row][packed_col_local]
    int bx = blockIdx.x;
    int tid = threadIdx.x;
    if (bx < 1152) {
        const float* W; u16* dst; int kc, uc, nk0;
        if (bx < 1024) { W = Wr; dst = BW;  kc = bx >> 2;          uc = bx & 3; nk0 = 64; }
        else           { W = Wk; dst = BWk; kc = (bx - 1024) >> 2; uc = (bx - 1024) & 3; nk0 = 8; }

        // fill: 8 rows; thread -> u-pair (u0 = uc*512 + tid*2); 4x float2 + 1x b128
        #pragma unroll
        for (int r = 0; r < 8; ++r) {
            const float* base = W + (size_t)(kc * 8 + r) * 8192 + uc * 512 + tid * 2;
            float2 v0 = *(const float2*)(base + 0 * 2048);
            float2 v1 = *(const float2*)(base + 1 * 2048);
            float2 v2 = *(const float2*)(base + 2 * 2048);
            float2 v3 = *(const float2*)(base + 3 * 2048);
            u16 o[8] = {to_bf16(v0.x), to_bf16(v1.x), to_bf16(v2.x), to_bf16(v3.x),
                        to_bf16(v0.y), to_bf16(v1.y), to_bf16(v2.y), to_bf16(v3.y)};
            *(uint4*)&lds[r][tid * 8] = *(uint4*)o;
        }
        __syncthreads();

        // assemble: band (kc&3) slice of 128 fragments; 8 per iter across 4 waves
        int w = tid >> 6, l = tid & 63, li = l & 15;
        int band = kc & 3, k0 = kc >> 2;
        #pragma unroll
        for (int i2 = 0; i2 < 8; ++i2) {
            int ntl = i2 * 16 + w * 4 + (l >> 4);
            u16 o[8];
            #pragma unroll
            for (int i = 0; i < 8; ++i) o[i] = lds[i][ntl * 16 + li];
            int nt = uc * 128 + ntl;
            *(uint4*)(dst + ((size_t)(nt * nk0 + k0) * 64 + band * 16 + li) * 8) = *(uint4*)o;
        }
    } else {
        int gidx = (bx - 1152) * 256 + tid;   // 0..4095
        int l = gidx & 63;
        int k0 = (gidx >> 6) & 7;
        int t = gidx >> 9;
        int b = l & 15;
        int tok = token_of(ip[b * LAT + t]);
        const float* s = E + (size_t)tok * EMB + k0 * 32 + 8 * (l >> 4);
        u16 o[8];
        #pragma unroll
        for (int i = 0; i < 8; ++i) o[i] = to_bf16(s[i]);
        *(uint4*)(XA + (size_t)gidx * 8) = *(uint4*)o;
    }
}

// ---- K2: xz GEMM for all 8 t (into xz[t][nt][b][n]) + fused step0.
// 512 blocks x 256 thr; wave w handles t = 2w, 2w+1. Block owns ntile nt.
__global__ __launch_bounds__(256) void k_xzmm0(
        const u16* __restrict__ BWk, const u16* __restrict__ XA,
        const float* __restrict__ bv, const float* __restrict__ ip,
        float* __restrict__ xz, float* __restrict__ H,
        float* __restrict__ c, u16* __restrict__ hA1) {
    int j = blockIdx.x;
    int nt = (j & 7) * 64 + (j >> 3);
    int tid = threadIdx.x;
    int w = tid >> 6, l = tid & 63;
    __shared__ float zsh0[256];

    int n = l & 15;
    float bias = bv[(n & 3) * 2048 + nt * 4 + (n >> 2)];

    const bf16x8* bp = (const bf16x8*)(BWk + ((size_t)(nt * 8) * 64 + l) * 8);
    bf16x8 bw[8];
    #pragma unroll
    for (int s = 0; s < 8; ++s) bw[s] = bp[s * 64];

    #pragma unroll
    for (int q = 0; q < 2; ++q) {
        int t = w * 2 + q;
        const bf16x8* ap = (const bf16x8*)(XA + ((size_t)(t * 8) * 64 + l) * 8);
        f32x4 acc = {bias, bias, bias, bias};
        #pragma unroll
        for (int s = 0; s < 8; ++s)
            acc = __builtin_amdgcn_mfma_f32_16x16x32_bf16(ap[s * 64], bw[s], acc, 0, 0, 0);
        #pragma unroll
        for (int i = 0; i < 4; ++i) {
            int b = 4 * (l >> 4) + i;   // D row = batch (m89-verified C/D layout)
            xz[(((size_t)t * 512 + nt) * 16 + b) * 16 + n] = acc[i];
            if (t == 0) zsh0[b * 16 + n] = acc[i];
        }
    }
    __syncthreads();

    // step0 update (h=c=0) for this block's 4 u's x 16 batches
    if (tid < 64) {
        int b = tid >> 2, ul = tid & 3;
        int myu = nt * 4 + ul;
        float z0 = zsh0[b * 16 + ul * 4 + 0];
        float z2 = zsh0[b * 16 + ul * 4 + 2];
        float z3 = zsh0[b * 16 + ul * 4 + 3];
        float cn = sigmoidf_(z0) * tanhf(z2);
        float hn = sigmoidf_(z3) * tanhf(cn);
        int tok = token_of(ip[b * LAT + 0]);
        float hw = tok != 0 ? hn : 0.0f;
        float cw = tok != 0 ? cn : 0.0f;
        c[b * 2048 + myu] = cw;
        H[b * 2048 + myu] = hw;
        u16 own = to_bf16(hw);
        int pair = __shfl_xor((int)own, 1);
        if (!(ul & 1)) {
            u32 val = (u32)own | ((u32)(u16)pair << 16);
            int k0 = myu >> 5, lg = (myu >> 3) & 3, i = myu & 7;
            *((u32*)hA1 + ((((k0 * 64) + lg * 16 + b) * 8 + i) >> 1)) = val;
        }
    }
}

// ---- K3: fused step t. 512 blocks x 512 thr = 8 waves (K-eighths).
__global__ __launch_bounds__(512) void k_step(
        const u16* __restrict__ BW,
        const u16* __restrict__ hAin, u16* __restrict__ hAout,
        const float* __restrict__ xz, const float* __restrict__ ip,
        float* __restrict__ c, float* __restrict__ H, int t) {
    int j = blockIdx.x;
    int nt = (j & 7) * 64 + (j >> 3);
    int tid = threadIdx.x;
    int kq = tid >> 6, l = tid & 63;     // kq = K-eighth (0..7)
    __shared__ float zsh[8][256];

    const bf16x8* ap = (const bf16x8*)(hAin + ((size_t)(kq * 8) * 64 + l) * 8);
    const bf16x8* bp = (const bf16x8*)(BW + (((size_t)(nt * 64) + kq * 8) * 64 + l) * 8);
    bf16x8 ar[8], br[8];
    #pragma unroll
    for (int i = 0; i < 8; ++i) { ar[i] = ap[i * 64]; br[i] = bp[i * 64]; }

    f32x4 acc = {0.f, 0.f, 0.f, 0.f};
    #pragma unroll
    for (int s = 0; s < 8; ++s)
        acc = __builtin_amdgcn_mfma_f32_16x16x32_bf16(ar[s], br[s], acc, 0, 0, 0);

    #pragma unroll
    for (int i = 0; i < 4; ++i)
        zsh[kq][(4 * (l >> 4) + i) * 16 + (l & 15)] = acc[i];
    __syncthreads();

    if (tid < 64) {
        int b = tid >> 2, ul = tid & 3;
        int myu = nt * 4 + ul;
        float4 xv = *(const float4*)&xz[(((size_t)t * 512 + nt) * 16 + b) * 16 + ul * 4];
        float z[4] = {xv.x, xv.y, xv.z, xv.w};
        #pragma unroll
        for (int kk = 0; kk < 8; ++kk) {
            float4 zv = *(const float4*)&zsh[kk][b * 16 + ul * 4];
            z[0] += zv.x; z[1] += zv.y; z[2] += zv.z; z[3] += zv.w;
        }
        int idx = b * 2048 + myu;
        float co = c[idx];
        float ho = H[((size_t)(t - 1) * 16 + b) * 2048 + myu];
        float cn = sigmoidf_(z[1]) * co + sigmoidf_(z[0]) * tanhf(z[2]);
        float hn = sigmoidf_(z[3]) * tanhf(cn);
        int tok = token_of(ip[b * LAT + t]);
        float hw = tok != 0 ? hn : ho;
        float cw = tok != 0 ? cn : co;
        c[idx] = cw;
        H[((size_t)t * 16 + b) * 2048 + myu] = hw;
        u16 own = to_bf16(hw);
        int pair = __shfl_xor((int)own, 1);
        if (!(ul & 1)) {
            u32 val = (u32)own | ((u32)(u16)pair << 16);
            int k0 = myu >> 5, lg = (myu >> 3) & 3, i = myu & 7;
            *((u32*)hAout + ((((k0 * 64) + lg * 16 + b) * 8 + i) >> 1)) = val;
        }
    }
}

// ---- K4: softmax of all 128 recorded h rows -> d_out[b][t][:] ----
__global__ __launch_bounds__(256) void k_softmax(const float* __restrict__ H,
                                                 float* __restrict__ out) {
    int r = blockIdx.x;          // r = t*16 + b
    int t = r >> 4, b = r & 15;
    int tid = threadIdx.x;
    const float* hr = H + (size_t)r * VOCAB;
    float v[8];
    float m = -1e30f;
    #pragma unroll
    for (int i = 0; i < 8; ++i) { v[i] = hr[tid + i * 256]; m = fmaxf(m, v[i]); }

    __shared__ float redm[4], reds[4];
    int wid = tid >> 6, lane = tid & 63;
    #pragma unroll
    for (int off = 32; off; off >>= 1) m = fmaxf(m, __shfl_down(m, off));
    if (lane == 0) redm[wid] = m;
    __syncthreads();
    m = fmaxf(fmaxf(redm[0], redm[1]), fmaxf(redm[2], redm[3]));

    float e[8];
    float s = 0.0f;
    #pragma unroll
    for (int i = 0; i < 8; ++i) { e[i] = expf(v[i] - m); s += e[i]; }
    #pragma unroll
    for (int off = 32; off; off >>= 1) s += __shfl_down(s, off);
    if (lane == 0) reds[wid] = s;
    __syncthreads();
    s = reds[0] + reds[1] + reds[2] + reds[3];

    float* o = out + ((size_t)b * MAXLEN + t) * VOCAB;
    #pragma unroll
    for (int i = 0; i < 8; ++i) o[tid + i * 256] = e[i] / s;
}

extern "C" void kernel_launch(void* const* d_in, const int* in_sizes, int n_in,
                              void* d_out, int out_size, void* d_ws, size_t ws_size,
                              hipStream_t stream) {
    const float* ip = (const float*)d_in[0];   // (16,16)
    const float* E  = (const float*)d_in[1];   // (2048,256)
    const float* Wk = (const float*)d_in[2];   // (256,8192)
    const float* Wr = (const float*)d_in[3];   // (2048,8192)
    const float* bv = (const float*)d_in[4];   // (8192,)

    char* w = (char*)d_ws;
    float* xz  = (float*)w;  w += (size_t)8 * 512 * 16 * 16 * 4;       // 4 MB
    float* H   = (float*)w;  w += (size_t)262144 * 4;                  // 1 MB
    float* c   = (float*)w;  w += (size_t)32768 * 4;                   // 128 KB
    u16* XA  = (u16*)w;      w += (size_t)32768 * 2;                   // 64 KB
    u16* hA0 = (u16*)w;      w += (size_t)32768 * 2;
    u16* hA1 = (u16*)w;      w += (size_t)32768 * 2;
    u16* BWk = (u16*)w;      w += (size_t)2097152 * 2;                 // 4 MB
    u16* BW  = (u16*)w;      w += (size_t)16777216 * 2;                // 32 MB

    k_pack<<<1168, 256, 0, stream>>>(Wr, Wk, ip, E, BW, BWk, XA);
    k_xzmm0<<<512, 256, 0, stream>>>(BWk, XA, bv, ip, xz, H, c, hA1);
    u16* hAbuf[2] = {hA0, hA1};
    for (int t = 1; t < MAXLEN; ++t)
        k_step<<<512, 512, 0, stream>>>(BW, hAbuf[t & 1], hAbuf[(t + 1) & 1],
                                        xz, ip, c, H, t);
    k_softmax<<<128, 256, 0, stream>>>(H, (float*)d_out);
}

// Round 19
// 70.555 us; speedup vs baseline: 1.0452x; 1.0452x over previous
//
#include <hip/hip_runtime.h>
#include <hip/hip_bf16.h>
#include <math.h>

#define VOCAB 2048
#define EMB 256
#define MAXLEN 8
#define NBATCH 16
#define LAT 16

typedef unsigned short u16;
typedef unsigned int u32;
using bf16x8 = __attribute__((ext_vector_type(8))) short;
using f32x4  = __attribute__((ext_vector_type(4))) float;

// token = argmax_j ( j/2048 <= v && v <= (j+1)/2048 ), 0 if none.
// cumsum of uniform softmax is exactly k/2048 in fp32; v*2048 is exact.
__device__ __forceinline__ int token_of(float v) {
    float u = v * 2048.0f;
    if (!(u >= 0.0f) || u > 2048.0f) return 0;   // v<0, v>1, or NaN
    int k = (int)ceilf(u) - 1;
    return k < 0 ? 0 : k;
}

__device__ __forceinline__ float sigmoidf_(float x) { return 1.0f / (1.0f + expf(-x)); }

__device__ __forceinline__ u16 to_bf16(float x) {
    __hip_bfloat16 hb = __float2bfloat16(x);   // RTNE
    return *reinterpret_cast<u16*>(&hb);
}

// ---------------------------------------------------------------------------
// GATE-INTERLEAVED column packing: packed col c = u*4 + g  (u=c>>2, g=c&3).
// One 16-col MFMA ntile = 4 u's x 4 gates -> LSTM update is block-local,
// enabling 512 independent blocks (full chip) in the recurrent step.
// Fragment (l,i) of (nt,k0): bf16( W[(k0*32 + 8*(l>>4) + i)*8192 + gcol ] ),
// gcol = ((l&15)&3)*2048 + nt*4 + ((l&15)>>2). A-frags use the same k-map,
// so any in-fragment k-permutation cancels.
// PACK tile = 32 rows x 512 packed cols (128 u x 4 gates), 32 KB LDS:
//  - reads: 512 B contiguous per (row,gate) per 32-lane group
//  - writes: 32 COMPLETE fragments (1 KB contiguous each)
//  - LDS: fill linear b128; assemble band-XOR key=((row>>3)&3)<<5 puts the
//    4 lane-groups in 4 disjoint bank octets (banks ((ntl^grp)%4)*8+0..7).
// Rounds 14-18 each missed one of the three -> pack stuck at 32-43 us.
// ---------------------------------------------------------------------------

// ---- K1: one-launch pack. [0,1024): Wr->BW; [1024,1152): Wk->BWk;
// [1152,1168): XA = E[token] A-fragments.
__global__ __launch_bounds__(256) void k_pack(
        const float* __restrict__ Wr, const float* __restrict__ Wk,
        const float* __restrict__ ip, const float* __restrict__ E,
        u16* __restrict__ BW, u16* __restrict__ BWk, u16* __restrict__ XA) {
    __shared__ __align__(16) u16 lds[32 * 512];   // 32 KB, row stride 1024 B
    int bx = blockIdx.x;
    int tid = threadIdx.x;
    if (bx < 1152) {
        const float* W; u16* dst; int kc, uc, nk0;
        if (bx < 1024) { W = Wr; dst = BW;  kc = bx >> 4;          uc = bx & 15; nk0 = 64; }
        else           { W = Wk; dst = BWk; kc = (bx - 1024) >> 4; uc = (bx - 1024) & 15; nk0 = 8; }

        // fill: 4 iters; thread -> (row r = lin>>5, u-quad ug = lin&31).
        // float4 per gate (512 B/gate per 32-lane group); 16 bf16 -> 32 B
        // stored at (ug*32)^key, key = ((r>>3)&3)<<5  (linear, conflict-free)
        #pragma unroll
        for (int it = 0; it < 4; ++it) {
            int lin = it * 256 + tid;
            int r = lin >> 5;
            int ug = lin & 31;
            const float* base = W + (size_t)(kc * 32 + r) * 8192 + uc * 128 + ug * 4;
            float4 v0 = *(const float4*)(base + 0 * 2048);
            float4 v1 = *(const float4*)(base + 1 * 2048);
            float4 v2 = *(const float4*)(base + 2 * 2048);
            float4 v3 = *(const float4*)(base + 3 * 2048);
            u16 o[16] = {to_bf16(v0.x), to_bf16(v1.x), to_bf16(v2.x), to_bf16(v3.x),
                         to_bf16(v0.y), to_bf16(v1.y), to_bf16(v2.y), to_bf16(v3.y),
                         to_bf16(v0.z), to_bf16(v1.z), to_bf16(v2.z), to_bf16(v3.z),
                         to_bf16(v0.w), to_bf16(v1.w), to_bf16(v2.w), to_bf16(v3.w)};
            int key = ((r >> 3) & 3) << 5;
            char* lp = (char*)lds + r * 1024 + ((ug * 32) ^ key);
            *(uint4*)lp       = *(uint4*)&o[0];
            *(uint4*)(lp + 16) = *(uint4*)&o[8];
        }
        __syncthreads();

        // assemble: 32 complete fragments (nt = uc*32 + ntl, k0 = kc);
        // 8 per thread-wave-slot; grp-XOR makes reads conflict-free.
        int w = tid >> 6, l = tid & 63;
        int li = l & 15, grp = l >> 4;
        #pragma unroll
        for (int i2 = 0; i2 < 8; ++i2) {
            int ntl = i2 * 4 + w;
            u16 o[8];
            #pragma unroll
            for (int i = 0; i < 8; ++i) {
                int rr = 8 * grp + i;
                o[i] = *(const u16*)((char*)lds + rr * 1024
                                     + ((ntl * 32 + li * 2) ^ (grp << 5)));
            }
            int nt = uc * 32 + ntl;
            *(uint4*)(dst + ((size_t)(nt * nk0 + kc) * 64 + l) * 8) = *(uint4*)o;
        }
    } else {
        int gidx = (bx - 1152) * 256 + tid;   // 0..4095
        int l = gidx & 63;
        int k0 = (gidx >> 6) & 7;
        int t = gidx >> 9;
        int b = l & 15;
        int tok = token_of(ip[b * LAT + t]);
        const float* s = E + (size_t)tok * EMB + k0 * 32 + 8 * (l >> 4);
        u16 o[8];
        #pragma unroll
        for (int i = 0; i < 8; ++i) o[i] = to_bf16(s[i]);
        *(uint4*)(XA + (size_t)gidx * 8) = *(uint4*)o;
    }
}

// ---- K2: xz GEMM for all 8 t (into xz[t][nt][b][n]) + fused step0.
// 512 blocks x 256 thr; wave w handles t = 2w, 2w+1. Block owns ntile nt.
__global__ __launch_bounds__(256) void k_xzmm0(
        const u16* __restrict__ BWk, const u16* __restrict__ XA,
        const float* __restrict__ bv, const float* __restrict__ ip,
        float* __restrict__ xz, float* __restrict__ H,
        float* __restrict__ c, u16* __restrict__ hA1) {
    int j = blockIdx.x;
    int nt = (j & 7) * 64 + (j >> 3);
    int tid = threadIdx.x;
    int w = tid >> 6, l = tid & 63;
    __shared__ float zsh0[256];

    int n = l & 15;
    float bias = bv[(n & 3) * 2048 + nt * 4 + (n >> 2)];

    const bf16x8* bp = (const bf16x8*)(BWk + ((size_t)(nt * 8) * 64 + l) * 8);
    bf16x8 bw[8];
    #pragma unroll
    for (int s = 0; s < 8; ++s) bw[s] = bp[s * 64];

    #pragma unroll
    for (int q = 0; q < 2; ++q) {
        int t = w * 2 + q;
        const bf16x8* ap = (const bf16x8*)(XA + ((size_t)(t * 8) * 64 + l) * 8);
        f32x4 acc = {bias, bias, bias, bias};
        #pragma unroll
        for (int s = 0; s < 8; ++s)
            acc = __builtin_amdgcn_mfma_f32_16x16x32_bf16(ap[s * 64], bw[s], acc, 0, 0, 0);
        #pragma unroll
        for (int i = 0; i < 4; ++i) {
            int b = 4 * (l >> 4) + i;   // D row = batch (m89-verified C/D layout)
            xz[(((size_t)t * 512 + nt) * 16 + b) * 16 + n] = acc[i];
            if (t == 0) zsh0[b * 16 + n] = acc[i];
        }
    }
    __syncthreads();

    // step0 update (h=c=0) for this block's 4 u's x 16 batches
    if (tid < 64) {
        int b = tid >> 2, ul = tid & 3;
        int myu = nt * 4 + ul;
        float z0 = zsh0[b * 16 + ul * 4 + 0];
        float z2 = zsh0[b * 16 + ul * 4 + 2];
        float z3 = zsh0[b * 16 + ul * 4 + 3];
        float cn = sigmoidf_(z0) * tanhf(z2);
        float hn = sigmoidf_(z3) * tanhf(cn);
        int tok = token_of(ip[b * LAT + 0]);
        float hw = tok != 0 ? hn : 0.0f;
        float cw = tok != 0 ? cn : 0.0f;
        c[b * 2048 + myu] = cw;
        H[b * 2048 + myu] = hw;
        u16 own = to_bf16(hw);
        int pair = __shfl_xor((int)own, 1);
        if (!(ul & 1)) {
            u32 val = (u32)own | ((u32)(u16)pair << 16);
            int k0 = myu >> 5, lg = (myu >> 3) & 3, i = myu & 7;
            *((u32*)hA1 + ((((k0 * 64) + lg * 16 + b) * 8 + i) >> 1)) = val;
        }
    }
}

// ---- K3: fused step t. 512 blocks x 512 thr = 8 waves (K-eighths).
__global__ __launch_bounds__(512) void k_step(
        const u16* __restrict__ BW,
        const u16* __restrict__ hAin, u16* __restrict__ hAout,
        const float* __restrict__ xz, const float* __restrict__ ip,
        float* __restrict__ c, float* __restrict__ H, int t) {
    int j = blockIdx.x;
    int nt = (j & 7) * 64 + (j >> 3);
    int tid = threadIdx.x;
    int kq = tid >> 6, l = tid & 63;     // kq = K-eighth (0..7)
    __shared__ float zsh[8][256];

    const bf16x8* ap = (const bf16x8*)(hAin + ((size_t)(kq * 8) * 64 + l) * 8);
    const bf16x8* bp = (const bf16x8*)(BW + (((size_t)(nt * 64) + kq * 8) * 64 + l) * 8);
    bf16x8 ar[8], br[8];
    #pragma unroll
    for (int i = 0; i < 8; ++i) { ar[i] = ap[i * 64]; br[i] = bp[i * 64]; }

    f32x4 acc = {0.f, 0.f, 0.f, 0.f};
    #pragma unroll
    for (int s = 0; s < 8; ++s)
        acc = __builtin_amdgcn_mfma_f32_16x16x32_bf16(ar[s], br[s], acc, 0, 0, 0);

    #pragma unroll
    for (int i = 0; i < 4; ++i)
        zsh[kq][(4 * (l >> 4) + i) * 16 + (l & 15)] = acc[i];
    __syncthreads();

    if (tid < 64) {
        int b = tid >> 2, ul = tid & 3;
        int myu = nt * 4 + ul;
        float4 xv = *(const float4*)&xz[(((size_t)t * 512 + nt) * 16 + b) * 16 + ul * 4];
        float z[4] = {xv.x, xv.y, xv.z, xv.w};
        #pragma unroll
        for (int kk = 0; kk < 8; ++kk) {
            float4 zv = *(const float4*)&zsh[kk][b * 16 + ul * 4];
            z[0] += zv.x; z[1] += zv.y; z[2] += zv.z; z[3] += zv.w;
        }
        int idx = b * 2048 + myu;
        float co = c[idx];
        float ho = H[((size_t)(t - 1) * 16 + b) * 2048 + myu];
        float cn = sigmoidf_(z[1]) * co + sigmoidf_(z[0]) * tanhf(z[2]);
        float hn = sigmoidf_(z[3]) * tanhf(cn);
        int tok = token_of(ip[b * LAT + t]);
        float hw = tok != 0 ? hn : ho;
        float cw = tok != 0 ? cn : co;
        c[idx] = cw;
        H[((size_t)t * 16 + b) * 2048 + myu] = hw;
        u16 own = to_bf16(hw);
        int pair = __shfl_xor((int)own, 1);
        if (!(ul & 1)) {
            u32 val = (u32)own | ((u32)(u16)pair << 16);
            int k0 = myu >> 5, lg = (myu >> 3) & 3, i = myu & 7;
            *((u32*)hAout + ((((k0 * 64) + lg * 16 + b) * 8 + i) >> 1)) = val;
        }
    }
}

// ---- K4: softmax of all 128 recorded h rows -> d_out[b][t][:] ----
__global__ __launch_bounds__(256) void k_softmax(const float* __restrict__ H,
                                                 float* __restrict__ out) {
    int r = blockIdx.x;          // r = t*16 + b
    int t = r >> 4, b = r & 15;
    int tid = threadIdx.x;
    const float* hr = H + (size_t)r * VOCAB;
    float v[8];
    float m = -1e30f;
    #pragma unroll
    for (int i = 0; i < 8; ++i) { v[i] = hr[tid + i * 256]; m = fmaxf(m, v[i]); }

    __shared__ float redm[4], reds[4];
    int wid = tid >> 6, lane = tid & 63;
    #pragma unroll
    for (int off = 32; off; off >>= 1) m = fmaxf(m, __shfl_down(m, off));
    if (lane == 0) redm[wid] = m;
    __syncthreads();
    m = fmaxf(fmaxf(redm[0], redm[1]), fmaxf(redm[2], redm[3]));

    float e[8];
    float s = 0.0f;
    #pragma unroll
    for (int i = 0; i < 8; ++i) { e[i] = expf(v[i] - m); s += e[i]; }
    #pragma unroll
    for (int off = 32; off; off >>= 1) s += __shfl_down(s, off);
    if (lane == 0) reds[wid] = s;
    __syncthreads();
    s = reds[0] + reds[1] + reds[2] + reds[3];

    float* o = out + ((size_t)b * MAXLEN + t) * VOCAB;
    #pragma unroll
    for (int i = 0; i < 8; ++i) o[tid + i * 256] = e[i] / s;
}

extern "C" void kernel_launch(void* const* d_in, const int* in_sizes, int n_in,
                              void* d_out, int out_size, void* d_ws, size_t ws_size,
                              hipStream_t stream) {
    const float* ip = (const float*)d_in[0];   // (16,16)
    const float* E  = (const float*)d_in[1];   // (2048,256)
    const float* Wk = (const float*)d_in[2];   // (256,8192)
    const float* Wr = (const float*)d_in[3];   // (2048,8192)
    const float* bv = (const float*)d_in[4];   // (8192,)

    char* w = (char*)d_ws;
    float* xz  = (float*)w;  w += (size_t)8 * 512 * 16 * 16 * 4;       // 4 MB
    float* H   = (float*)w;  w += (size_t)262144 * 4;                  // 1 MB
    float* c   = (float*)w;  w += (size_t)32768 * 4;                   // 128 KB
    u16* XA  = (u16*)w;      w += (size_t)32768 * 2;                   // 64 KB
    u16* hA0 = (u16*)w;      w += (size_t)32768 * 2;
    u16* hA1 = (u16*)w;      w += (size_t)32768 * 2;
    u16* BWk = (u16*)w;      w += (size_t)2097152 * 2;                 // 4 MB
    u16* BW  = (u16*)w;      w += (size_t)16777216 * 2;                // 32 MB

    k_pack<<<1168, 256, 0, stream>>>(Wr, Wk, ip, E, BW, BWk, XA);
    k_xzmm0<<<512, 256, 0, stream>>>(BWk, XA, bv, ip, xz, H, c, hA1);
    u16* hAbuf[2] = {hA0, hA1};
    for (int t = 1; t < MAXLEN; ++t)
        k_step<<<512, 512, 0, stream>>>(BW, hAbuf[t & 1], hAbuf[(t + 1) & 1],
                                        xz, ip, c, H, t);
    k_softmax<<<128, 256, 0, stream>>>(H, (float*)d_out);
}

// Round 20
// 69.968 us; speedup vs baseline: 1.0540x; 1.0084x over previous
//
#include <hip/hip_runtime.h>
#include <hip/hip_bf16.h>
#include <math.h>

#define VOCAB 2048
#define EMB 256
#define MAXLEN 8
#define NBATCH 16
#define LAT 16

typedef unsigned short u16;
typedef unsigned int u32;
typedef unsigned long long u64;
using bf16x8 = __attribute__((ext_vector_type(8))) short;
using f32x4  = __attribute__((ext_vector_type(4))) float;

// token = argmax_j ( j/2048 <= v && v <= (j+1)/2048 ), 0 if none.
// cumsum of uniform softmax is exactly k/2048 in fp32; v*2048 is exact.
__device__ __forceinline__ int token_of(float v) {
    float u = v * 2048.0f;
    if (!(u >= 0.0f) || u > 2048.0f) return 0;   // v<0, v>1, or NaN
    int k = (int)ceilf(u) - 1;
    return k < 0 ? 0 : k;
}

__device__ __forceinline__ float sigmoidf_(float x) { return 1.0f / (1.0f + expf(-x)); }

__device__ __forceinline__ u16 to_bf16(float x) {
    __hip_bfloat16 hb = __float2bfloat16(x);   // RTNE
    return *reinterpret_cast<u16*>(&hb);
}

// ---------------------------------------------------------------------------
// GATE-INTERLEAVED column packing: packed col c = u*4 + g  (u=c>>2, g=c&3).
// One 16-col MFMA ntile = 4 u's x 4 gates -> LSTM update is block-local,
// enabling 512 independent blocks (full chip) in the recurrent step.
// Fragment (l,i) of (nt,k0): bf16( W[(k0*32 + 8*(l>>4) + i)*8192 + gcol ] ),
// gcol = ((l&15)&3)*2048 + nt*4 + ((l&15)>>2). A-frags use the same k-map,
// so any in-fragment k-permutation cancels.
//
// PACK lesson (rounds 15-19, all ~33 us invariant): the pack is
// DS-INSTRUCTION-ISSUE bound — one scalar ds_read_u16 per element = 18.9M
// reads. Tiling/conflicts don't matter; op count does. Fix: subtiled LDS
// (4 rows x 16 cols per slot, pitch 176 B) + ds_read_b64_tr_b16 hardware
// transpose (per-lane addr; 4 elems at +{0,32,64,96} B — m156/m162): a
// fragment's 8 elems = 2 tr-reads. DS ops/thread: 72 -> 24.
// ---------------------------------------------------------------------------

#define SLOT_PITCH 176          // 16B-aligned; bank-quad = 12*ct mod 32 (8 quads)
#define TR_OFF (32 * SLOT_PITCH) // slot (sr+1,ct) - slot (sr,ct) = 5632 B

// ---- K1: one-launch pack. [0,1024): Wr->BW; [1024,1152): Wk->BWk;
// [1152,1168): XA = E[token] A-fragments.
__global__ __launch_bounds__(256) void k_pack(
        const float* __restrict__ Wr, const float* __restrict__ Wk,
        const float* __restrict__ ip, const float* __restrict__ E,
        u16* __restrict__ BW, u16* __restrict__ BWk, u16* __restrict__ XA) {
    __shared__ __align__(16) char lds[256 * SLOT_PITCH];   // 44 KB
    int bx = blockIdx.x;
    int tid = threadIdx.x;
    if (bx < 1152) {
        const float* W; u16* dst; int kc, uc, nk0;
        if (bx < 1024) { W = Wr; dst = BW;  kc = bx >> 4;          uc = bx & 15; nk0 = 64; }
        else           { W = Wk; dst = BWk; kc = (bx - 1024) >> 4; uc = (bx - 1024) & 15; nk0 = 8; }

        // fill: 4 iters; item (r = lin>>5, ug = lin&31). float4 per gate
        // (512B contiguous per 32-lane group); 16 bf16 = cols ug*16..+15 of
        // row r -> subtile (r>>2, ug), bytes (r&3)*32 .. +31: 2x b128.
        #pragma unroll
        for (int it = 0; it < 4; ++it) {
            int lin = it * 256 + tid;
            int r = lin >> 5;
            int ug = lin & 31;
            const float* base = W + (size_t)(kc * 32 + r) * 8192 + uc * 128 + ug * 4;
            float4 v0 = *(const float4*)(base + 0 * 2048);
            float4 v1 = *(const float4*)(base + 1 * 2048);
            float4 v2 = *(const float4*)(base + 2 * 2048);
            float4 v3 = *(const float4*)(base + 3 * 2048);
            u16 o[16] = {to_bf16(v0.x), to_bf16(v1.x), to_bf16(v2.x), to_bf16(v3.x),
                         to_bf16(v0.y), to_bf16(v1.y), to_bf16(v2.y), to_bf16(v3.y),
                         to_bf16(v0.z), to_bf16(v1.z), to_bf16(v2.z), to_bf16(v3.z),
                         to_bf16(v0.w), to_bf16(v1.w), to_bf16(v2.w), to_bf16(v3.w)};
            char* lp = lds + ((r >> 2) * 32 + ug) * SLOT_PITCH + (r & 3) * 32;
            *(uint4*)lp        = *(uint4*)&o[0];
            *(uint4*)(lp + 16) = *(uint4*)&o[8];
        }
        __syncthreads();

        // assemble: 8 fragments/thread; per fragment TWO ds_read_b64_tr_b16
        // (rows 8g..+3 and +4..+7 of col ntl*16+li), lgkmcnt(0) in-asm so the
        // dependent store is data-ordered.
        int w = tid >> 6, l = tid & 63;
        int li = l & 15, grp = l >> 4;
        unsigned lbase = (unsigned)(size_t)(&lds[0]);
        #pragma unroll
        for (int i2 = 0; i2 < 8; ++i2) {
            int ntl = i2 * 4 + w;
            unsigned addr = lbase + (unsigned)(((2 * grp) * 32 + ntl) * SLOT_PITCH + li * 2);
            u64 t0, t1;
            asm volatile(
                "ds_read_b64_tr_b16 %0, %2 offset:0\n\t"
                "ds_read_b64_tr_b16 %1, %2 offset:5632\n\t"
                "s_waitcnt lgkmcnt(0)"
                : "=v"(t0), "=v"(t1) : "v"(addr) : "memory");
            uint4 fr;
            fr.x = (u32)t0; fr.y = (u32)(t0 >> 32);
            fr.z = (u32)t1; fr.w = (u32)(t1 >> 32);
            int nt = uc * 32 + ntl;
            *(uint4*)(dst + ((size_t)(nt * nk0 + kc) * 64 + l) * 8) = fr;
        }
    } else {
        int gidx = (bx - 1152) * 256 + tid;   // 0..4095
        int l = gidx & 63;
        int k0 = (gidx >> 6) & 7;
        int t = gidx >> 9;
        int b = l & 15;
        int tok = token_of(ip[b * LAT + t]);
        const float* s = E + (size_t)tok * EMB + k0 * 32 + 8 * (l >> 4);
        u16 o[8];
        #pragma unroll
        for (int i = 0; i < 8; ++i) o[i] = to_bf16(s[i]);
        *(uint4*)(XA + (size_t)gidx * 8) = *(uint4*)o;
    }
}

// ---- K2: xz GEMM for all 8 t (into xz[t][nt][b][n]) + fused step0.
// 512 blocks x 256 thr; wave w handles t = 2w, 2w+1. Block owns ntile nt.
__global__ __launch_bounds__(256) void k_xzmm0(
        const u16* __restrict__ BWk, const u16* __restrict__ XA,
        const float* __restrict__ bv, const float* __restrict__ ip,
        float* __restrict__ xz, float* __restrict__ H,
        float* __restrict__ c, u16* __restrict__ hA1) {
    int j = blockIdx.x;
    int nt = (j & 7) * 64 + (j >> 3);
    int tid = threadIdx.x;
    int w = tid >> 6, l = tid & 63;
    __shared__ float zsh0[256];

    int n = l & 15;
    float bias = bv[(n & 3) * 2048 + nt * 4 + (n >> 2)];

    const bf16x8* bp = (const bf16x8*)(BWk + ((size_t)(nt * 8) * 64 + l) * 8);
    bf16x8 bw[8];
    #pragma unroll
    for (int s = 0; s < 8; ++s) bw[s] = bp[s * 64];

    #pragma unroll
    for (int q = 0; q < 2; ++q) {
        int t = w * 2 + q;
        const bf16x8* ap = (const bf16x8*)(XA + ((size_t)(t * 8) * 64 + l) * 8);
        f32x4 acc = {bias, bias, bias, bias};
        #pragma unroll
        for (int s = 0; s < 8; ++s)
            acc = __builtin_amdgcn_mfma_f32_16x16x32_bf16(ap[s * 64], bw[s], acc, 0, 0, 0);
        #pragma unroll
        for (int i = 0; i < 4; ++i) {
            int b = 4 * (l >> 4) + i;   // D row = batch (m89-verified C/D layout)
            xz[(((size_t)t * 512 + nt) * 16 + b) * 16 + n] = acc[i];
            if (t == 0) zsh0[b * 16 + n] = acc[i];
        }
    }
    __syncthreads();

    // step0 update (h=c=0) for this block's 4 u's x 16 batches
    if (tid < 64) {
        int b = tid >> 2, ul = tid & 3;
        int myu = nt * 4 + ul;
        float z0 = zsh0[b * 16 + ul * 4 + 0];
        float z2 = zsh0[b * 16 + ul * 4 + 2];
        float z3 = zsh0[b * 16 + ul * 4 + 3];
        float cn = sigmoidf_(z0) * tanhf(z2);
        float hn = sigmoidf_(z3) * tanhf(cn);
        int tok = token_of(ip[b * LAT + 0]);
        float hw = tok != 0 ? hn : 0.0f;
        float cw = tok != 0 ? cn : 0.0f;
        c[b * 2048 + myu] = cw;
        H[b * 2048 + myu] = hw;
        u16 own = to_bf16(hw);
        int pair = __shfl_xor((int)own, 1);
        if (!(ul & 1)) {
            u32 val = (u32)own | ((u32)(u16)pair << 16);
            int k0 = myu >> 5, lg = (myu >> 3) & 3, i = myu & 7;
            *((u32*)hA1 + ((((k0 * 64) + lg * 16 + b) * 8 + i) >> 1)) = val;
        }
    }
}

// ---- K3: fused step t. 512 blocks x 512 thr = 8 waves (K-eighths).
__global__ __launch_bounds__(512) void k_step(
        const u16* __restrict__ BW,
        const u16* __restrict__ hAin, u16* __restrict__ hAout,
        const float* __restrict__ xz, const float* __restrict__ ip,
        float* __restrict__ c, float* __restrict__ H, int t) {
    int j = blockIdx.x;
    int nt = (j & 7) * 64 + (j >> 3);
    int tid = threadIdx.x;
    int kq = tid >> 6, l = tid & 63;     // kq = K-eighth (0..7)
    __shared__ float zsh[8][256];

    const bf16x8* ap = (const bf16x8*)(hAin + ((size_t)(kq * 8) * 64 + l) * 8);
    const bf16x8* bp = (const bf16x8*)(BW + (((size_t)(nt * 64) + kq * 8) * 64 + l) * 8);
    bf16x8 ar[8], br[8];
    #pragma unroll
    for (int i = 0; i < 8; ++i) { ar[i] = ap[i * 64]; br[i] = bp[i * 64]; }

    f32x4 acc = {0.f, 0.f, 0.f, 0.f};
    #pragma unroll
    for (int s = 0; s < 8; ++s)
        acc = __builtin_amdgcn_mfma_f32_16x16x32_bf16(ar[s], br[s], acc, 0, 0, 0);

    #pragma unroll
    for (int i = 0; i < 4; ++i)
        zsh[kq][(4 * (l >> 4) + i) * 16 + (l & 15)] = acc[i];
    __syncthreads();

    if (tid < 64) {
        int b = tid >> 2, ul = tid & 3;
        int myu = nt * 4 + ul;
        float4 xv = *(const float4*)&xz[(((size_t)t * 512 + nt) * 16 + b) * 16 + ul * 4];
        float z[4] = {xv.x, xv.y, xv.z, xv.w};
        #pragma unroll
        for (int kk = 0; kk < 8; ++kk) {
            float4 zv = *(const float4*)&zsh[kk][b * 16 + ul * 4];
            z[0] += zv.x; z[1] += zv.y; z[2] += zv.z; z[3] += zv.w;
        }
        int idx = b * 2048 + myu;
        float co = c[idx];
        float ho = H[((size_t)(t - 1) * 16 + b) * 2048 + myu];
        float cn = sigmoidf_(z[1]) * co + sigmoidf_(z[0]) * tanhf(z[2]);
        float hn = sigmoidf_(z[3]) * tanhf(cn);
        int tok = token_of(ip[b * LAT + t]);
        float hw = tok != 0 ? hn : ho;
        float cw = tok != 0 ? cn : co;
        c[idx] = cw;
        H[((size_t)t * 16 + b) * 2048 + myu] = hw;
        u16 own = to_bf16(hw);
        int pair = __shfl_xor((int)own, 1);
        if (!(ul & 1)) {
            u32 val = (u32)own | ((u32)(u16)pair << 16);
            int k0 = myu >> 5, lg = (myu >> 3) & 3, i = myu & 7;
            *((u32*)hAout + ((((k0 * 64) + lg * 16 + b) * 8 + i) >> 1)) = val;
        }
    }
}

// ---- K4: softmax of all 128 recorded h rows -> d_out[b][t][:] ----
__global__ __launch_bounds__(256) void k_softmax(const float* __restrict__ H,
                                                 float* __restrict__ out) {
    int r = blockIdx.x;          // r = t*16 + b
    int t = r >> 4, b = r & 15;
    int tid = threadIdx.x;
    const float* hr = H + (size_t)r * VOCAB;
    float v[8];
    float m = -1e30f;
    #pragma unroll
    for (int i = 0; i < 8; ++i) { v[i] = hr[tid + i * 256]; m = fmaxf(m, v[i]); }

    __shared__ float redm[4], reds[4];
    int wid = tid >> 6, lane = tid & 63;
    #pragma unroll
    for (int off = 32; off; off >>= 1) m = fmaxf(m, __shfl_down(m, off));
    if (lane == 0) redm[wid] = m;
    __syncthreads();
    m = fmaxf(fmaxf(redm[0], redm[1]), fmaxf(redm[2], redm[3]));

    float e[8];
    float s = 0.0f;
    #pragma unroll
    for (int i = 0; i < 8; ++i) { e[i] = expf(v[i] - m); s += e[i]; }
    #pragma unroll
    for (int off = 32; off; off >>= 1) s += __shfl_down(s, off);
    if (lane == 0) reds[wid] = s;
    __syncthreads();
    s = reds[0] + reds[1] + reds[2] + reds[3];

    float* o = out + ((size_t)b * MAXLEN + t) * VOCAB;
    #pragma unroll
    for (int i = 0; i < 8; ++i) o[tid + i * 256] = e[i] / s;
}

extern "C" void kernel_launch(void* const* d_in, const int* in_sizes, int n_in,
                              void* d_out, int out_size, void* d_ws, size_t ws_size,
                              hipStream_t stream) {
    const float* ip = (const float*)d_in[0];   // (16,16)
    const float* E  = (const float*)d_in[1];   // (2048,256)
    const float* Wk = (const float*)d_in[2];   // (256,8192)
    const float* Wr = (const float*)d_in[3];   // (2048,8192)
    const float* bv = (const float*)d_in[4];   // (8192,)

    char* w = (char*)d_ws;
    float* xz  = (float*)w;  w += (size_t)8 * 512 * 16 * 16 * 4;       // 4 MB
    float* H   = (float*)w;  w += (size_t)262144 * 4;                  // 1 MB
    float* c   = (float*)w;  w += (size_t)32768 * 4;                   // 128 KB
    u16* XA  = (u16*)w;      w += (size_t)32768 * 2;                   // 64 KB
    u16* hA0 = (u16*)w;      w += (size_t)32768 * 2;
    u16* hA1 = (u16*)w;      w += (size_t)32768 * 2;
    u16* BWk = (u16*)w;      w += (size_t)2097152 * 2;                 // 4 MB
    u16* BW  = (u16*)w;      w += (size_t)16777216 * 2;                // 32 MB

    k_pack<<<1168, 256, 0, stream>>>(Wr, Wk, ip, E, BW, BWk, XA);
    k_xzmm0<<<512, 256, 0, stream>>>(BWk, XA, bv, ip, xz, H, c, hA1);
    u16* hAbuf[2] = {hA0, hA1};
    for (int t = 1; t < MAXLEN; ++t)
        k_step<<<512, 512, 0, stream>>>(BW, hAbuf[t & 1], hAbuf[(t + 1) & 1],
                                        xz, ip, c, H, t);
    k_softmax<<<128, 256, 0, stream>>>(H, (float*)d_out);
}